// Round 2
// baseline (284.949 us; speedup 1.0000x reference)
//
#include <hip/hip_runtime.h>
#include <math.h>

// ---------------------------------------------------------------------------
// SingleHeadSelfAttention: B=4, S=2048, C=2048, d=512
// R8: same 256x256 / 8-wave / 4-slot-ring core as R7, but the K-loop is
//     restructured to the m201 8-phase schedule: per 32-col chunk, TWO
//     16-MFMA sub-phases each {ds_read subtile + 2 gl_lds stage -> s_barrier
//     -> lgkmcnt(0) -> setprio(1) 16xMFMA setprio(0) -> s_barrier}, counted
//     vmcnt(8) once per chunk. R7's single-barrier 32-MFMA monophase
//     serialized the LDS burst (1156 cy/CU) with the MFMA burst (1242 cy/CU)
//     -> phase 2456 cy, MfmaUtil 31%. The fine interleave + double barrier +
//     setprio creates the wave role-split that overlaps the two pipes.
// ---------------------------------------------------------------------------

typedef __bf16 bf16;
typedef bf16 bf16x8 __attribute__((ext_vector_type(8)));
typedef bf16 bf16x4 __attribute__((ext_vector_type(4)));
typedef float f32x4 __attribute__((ext_vector_type(4)));

#define BB 4
#define SS 2048
#define CC 2048
#define DD 512
#define ND3 1536          // 3*DD
#define MM 8192           // BB*SS

typedef const __attribute__((address_space(1))) unsigned int g_u32;
typedef __attribute__((address_space(3))) unsigned int l_u32;

__device__ __forceinline__ void gl_lds16(const bf16* g, bf16* l) {
    __builtin_amdgcn_global_load_lds((g_u32*)g, (l_u32*)l, 16, 0, 0);
}

// ---------------- prep: fp32->bf16 for x/Wqkv/Wo + zero rsum ---------------
#define N4_X   (MM * CC / 4)          // 4194304
#define N4_WQ  (ND3 * CC / 4)         //  786432
#define N4_WO  (CC * DD / 4)          //  262144
#define N4_RS  (MM / 4)               //    2048
#define N4_TOT (N4_X + N4_WQ + N4_WO + N4_RS)

__global__ __launch_bounds__(256) void prep(const float* __restrict__ x,
                                            const float* __restrict__ Wqkv,
                                            const float* __restrict__ Wo,
                                            bf16* __restrict__ xb,
                                            bf16* __restrict__ wqkvb,
                                            bf16* __restrict__ wob,
                                            float* __restrict__ rsum) {
    int i = blockIdx.x * 256 + threadIdx.x;
    const int stride = gridDim.x * 256;
    for (; i < N4_TOT; i += stride) {
        if (i < N4_X + N4_WQ + N4_WO) {
            const float* src; bf16* dst; int j = i;
            if (j < N4_X)                { src = x;    dst = xb; }
            else if (j < N4_X + N4_WQ)   { src = Wqkv; dst = wqkvb; j -= N4_X; }
            else                         { src = Wo;   dst = wob;   j -= N4_X + N4_WQ; }
            float4 v = ((const float4*)src)[j];
            bf16x4 o;
            o[0] = (bf16)v.x; o[1] = (bf16)v.y; o[2] = (bf16)v.z; o[3] = (bf16)v.w;
            ((bf16x4*)dst)[j] = o;
        } else {
            int j = i - (N4_X + N4_WQ + N4_WO);
            ((float4*)rsum)[j] = float4{0.f, 0.f, 0.f, 0.f};
        }
    }
}

// ---------------------------------------------------------------------------
// 256x256-tile core, 8 waves (2Mx4N), per-wave 128x64 output (acc[8][4]).
// K pipelined in 32-col chunks through a 4-slot LDS ring (128 KiB dynamic).
// Chunk j, steady state (outstanding at entry = chunks j+1,j+2 = 8 loads):
//   ph0: ds_read af[0..3]+bfr[0..3] (8xb128) | STAGE_A(j+3) (2 gl_lds)
//        s_barrier; lgkmcnt(0); setprio1; 16 MFMA (i=0..3); setprio0; s_barrier
//   ph1: ds_read af[4..7] (4xb128, bfr in regs) | STAGE_B(j+3) (2 gl_lds)
//        s_barrier; lgkmcnt(0); setprio1; 16 MFMA (i=4..7); setprio0;
//        vmcnt(8); s_barrier
// vmcnt(8) leaves chunks j+2,j+3 in flight => chunk j+1 landed for next chunk.
// Slot overwrite safe: every wave drains lgkmcnt(0) before each chunk's final
// barrier, so all reads of slot (j-1)&3 COMPLETED before STAGE into it.
// Swizzle (both-sides involution): LDS dest linear (global_load_lds req);
// global SOURCE col-slot = s ^ ((row>>1)&3); read applies the same XOR.
// ---------------------------------------------------------------------------
#define SLOT_E 16384      // elements per ring slot (A 8192 + B 8192)
#define CH_B   8192

#define CHUNK_BODY(j, DO_STAGE)                                               \
    {                                                                         \
        const bf16* sa = lds + ((j) & 3) * SLOT_E + (wm + cl) * 32 + swzr;    \
        const bf16* sb = lds + ((j) & 3) * SLOT_E + CH_B + (wn + cl) * 32 + swzr; \
        bf16x8 af[4], bfr[4];                                                 \
        _Pragma("unroll") for (int i = 0; i < 4; i++)                         \
            af[i] = *(const bf16x8*)(sa + i * 512);                           \
        _Pragma("unroll") for (int jj = 0; jj < 4; jj++)                      \
            bfr[jj] = *(const bf16x8*)(sb + jj * 512);                        \
        if (DO_STAGE) STAGE_A((j) + 3);                                       \
        __builtin_amdgcn_s_barrier();                                         \
        asm volatile("s_waitcnt lgkmcnt(0)" ::: "memory");                    \
        __builtin_amdgcn_s_setprio(1);                                        \
        _Pragma("unroll") for (int i = 0; i < 4; i++)                         \
            _Pragma("unroll") for (int jj = 0; jj < 4; jj++)                  \
                acc[i][jj] = __builtin_amdgcn_mfma_f32_16x16x32_bf16(         \
                                 af[i], bfr[jj], acc[i][jj], 0, 0, 0);        \
        __builtin_amdgcn_s_setprio(0);                                        \
        __builtin_amdgcn_s_barrier();                                         \
        _Pragma("unroll") for (int i = 0; i < 4; i++)                         \
            af[i] = *(const bf16x8*)(sa + (4 + i) * 512);                     \
        if (DO_STAGE) STAGE_B((j) + 3);                                       \
        __builtin_amdgcn_s_barrier();                                         \
        asm volatile("s_waitcnt lgkmcnt(0)" ::: "memory");                    \
        __builtin_amdgcn_s_setprio(1);                                        \
        _Pragma("unroll") for (int i = 0; i < 4; i++)                         \
            _Pragma("unroll") for (int jj = 0; jj < 4; jj++)                  \
                acc[4 + i][jj] = __builtin_amdgcn_mfma_f32_16x16x32_bf16(     \
                                 af[i], bfr[jj], acc[4 + i][jj], 0, 0, 0);    \
        __builtin_amdgcn_s_setprio(0);                                        \
    }

template <bool OUT_BF16, int EPI>
__device__ __forceinline__ void gemm256_body(const bf16* __restrict__ A,
                                             const bf16* __restrict__ Bm,
                                             const float* __restrict__ bias,
                                             float* __restrict__ rowsum,
                                             bf16* __restrict__ vTp,
                                             void* __restrict__ Cv,
                                             int K, int lda, int ldb, int ldc,
                                             long ab, long bb, long cb,
                                             float scale) {
    extern __shared__ bf16 lds[];
    A  += (size_t)blockIdx.z * ab;
    Bm += (size_t)blockIdx.z * bb;
    const int m0 = blockIdx.y * 256, n0 = blockIdx.x * 256;
    const int t = threadIdx.x, lane = t & 63, w = t >> 6;
    const int wm = (w >> 2) * 128, wn = (w & 3) * 64;
    const int cl = lane & 15, q = lane >> 4;
    const int swzr = (q ^ ((cl >> 1) & 3)) * 8;        // read-side XOR swizzle
    // staging: thread t covers LDS (row=t>>2, 16B-slot=t&3) of a 128-row half;
    // fetches global col-slot (t&3) ^ ((t>>3)&3) = s ^ ((row>>1)&3).
    const int srow = t >> 2;
    const int swz  = (t & 3) ^ ((t >> 3) & 3);
    const bf16* pa = A  + (size_t)(m0 + srow) * lda + swz * 8;
    const bf16* pb = Bm + (size_t)(n0 + srow) * ldb + swz * 8;
    bf16* lw = lds + w * 512;                          // wave-uniform LDS base

    f32x4 acc[8][4] = {};
    const int NC = K >> 5;                             // K / 32 chunks (>= 4)

    auto STAGE_A = [&](int j) {
        bf16* s = lw + (j & 3) * SLOT_E;
        const bf16* ga = pa + j * 32;
        gl_lds16(ga,                     s);
        gl_lds16(ga + (size_t)128 * lda, s + 4096);
    };
    auto STAGE_B = [&](int j) {
        bf16* s = lw + (j & 3) * SLOT_E + CH_B;
        const bf16* gb = pb + j * 32;
        gl_lds16(gb,                     s);
        gl_lds16(gb + (size_t)128 * ldb, s + 4096);
    };

    // prologue: 3 chunks issued, wait chunk 0 (8 = chunks 1,2 in flight)
    STAGE_A(0); STAGE_B(0);
    STAGE_A(1); STAGE_B(1);
    STAGE_A(2); STAGE_B(2);
    asm volatile("s_waitcnt vmcnt(8)" ::: "memory");
    __builtin_amdgcn_s_barrier();

    for (int j = 0; j < NC - 3; ++j) {
        CHUNK_BODY(j, true);
        asm volatile("s_waitcnt vmcnt(8)" ::: "memory");
        __builtin_amdgcn_s_barrier();
    }
    CHUNK_BODY(NC - 3, false);
    asm volatile("s_waitcnt vmcnt(4)" ::: "memory");
    __builtin_amdgcn_s_barrier();
    CHUNK_BODY(NC - 2, false);
    asm volatile("s_waitcnt vmcnt(0)" ::: "memory");
    __builtin_amdgcn_s_barrier();
    CHUNK_BODY(NC - 1, false);

    // ---------------- epilogues --------------------------------------------
    if constexpr (EPI == 4) {          // scoresT: exp, packed C^T, col-sums
        float cs[4] = {0.f, 0.f, 0.f, 0.f};
#pragma unroll
        for (int i = 0; i < 8; i++)
#pragma unroll
            for (int jj = 0; jj < 4; jj++) {
                int col = n0 + wn + jj * 16 + cl;
                int row = m0 + wm + i * 16 + q * 4;
                bf16x4 o;
#pragma unroll
                for (int r = 0; r < 4; r++) {
                    float e = __expf(acc[i][jj][r] * scale);
                    cs[jj] += e;
                    o[r] = (bf16)e;
                }
                *(bf16x4*)&((bf16*)Cv)[(size_t)blockIdx.z * cb + (size_t)col * ldc + row] = o;
            }
#pragma unroll
        for (int jj = 0; jj < 4; jj++) {
            cs[jj] += __shfl_xor(cs[jj], 16, 64);
            cs[jj] += __shfl_xor(cs[jj], 32, 64);
        }
        if (q == 0) {
#pragma unroll
            for (int jj = 0; jj < 4; jj++)
                atomicAdd(&rowsum[(size_t)blockIdx.z * SS + n0 + wn + jj * 16 + cl], cs[jj]);
        }
        return;
    }

    const bool v_block = (EPI == 3) && (n0 >= 1024);
#pragma unroll
    for (int i = 0; i < 8; i++) {
#pragma unroll
        for (int jj = 0; jj < 4; jj++) {
            int col = n0 + wn + jj * 16 + cl;
            float bvv = bias ? bias[col] : 0.0f;
            if (v_block) {
                int row = m0 + wm + i * 16 + q * 4;
                int b = row >> 11, s = row & 2047;
                bf16x4 o;
#pragma unroll
                for (int r = 0; r < 4; r++) o[r] = (bf16)(acc[i][jj][r] * scale + bvv);
                *(bf16x4*)&vTp[((size_t)b * DD + (col - 1024)) * SS + s] = o;
            } else {
#pragma unroll
                for (int r = 0; r < 4; r++) {
                    int row = m0 + wm + i * 16 + q * 4 + r;
                    float val = acc[i][jj][r] * scale + bvv;
                    if (OUT_BF16)
                        ((bf16*)Cv)[(size_t)blockIdx.z * cb + (size_t)row * ldc + col] = (bf16)val;
                    else
                        ((float*)Cv)[(size_t)blockIdx.z * cb + (size_t)row * ldc + col] = val;
                }
            }
        }
    }
}

// ---------------------------------------------------------------------------
// OLD 128-tile core (verified) -- kept for k_pv only (BN=64, EPI=5).
// ---------------------------------------------------------------------------
template <bool OUT_BF16, int BN, int EPI>
__device__ __forceinline__ void gemm_body(const bf16* __restrict__ A,
                                          const bf16* __restrict__ Bm,
                                          const float* __restrict__ bias,
                                          float* __restrict__ rowsum,
                                          bf16* __restrict__ vTp,
                                          void* __restrict__ Cv,
                                          int K, int lda, int ldb, int ldc,
                                          long ab, long bb, long cb,
                                          float scale) {
    constexpr int TM = (BN == 128) ? 4 : 2;
    constexpr int NB = (BN == 128) ? 4 : 2;
    __shared__ bf16 As[128 * 64];
    __shared__ bf16 Bs[BN * 64];
    A += (size_t)blockIdx.z * ab;
    Bm += (size_t)blockIdx.z * bb;
    const int m0 = blockIdx.y * 128, n0 = blockIdx.x * BN;
    const int t = threadIdx.x, lane = t & 63, w = t >> 6;
    const int wm = (BN == 128) ? (w >> 1) * 64 : w * 32;
    const int wn = (BN == 128) ? (w & 1) * 64 : 0;
    const int q = lane >> 4, cl = lane & 15;
    const int srow = lane >> 3;
    const int sblk = (lane & 7) ^ srow;
    const int scol = sblk * 8;
    const bf16* pa = A + (size_t)(m0 + w * 32 + srow) * lda + scol;
    const int brow0 = (BN == 128) ? w * 32 : w * 16;
    const bf16* pb = Bm + (size_t)(n0 + brow0 + srow) * ldb + scol;
    bf16* lA = As + (w * 32) * 64;
    bf16* lB = Bs + brow0 * 64;
    const int rblk0 = (q ^ (cl & 7)) * 8;
    const int rblk1 = ((4 + q) ^ (cl & 7)) * 8;

    f32x4 acc[TM][4] = {};
    for (int k0 = 0; k0 < K; k0 += 64) {
#pragma unroll
        for (int n = 0; n < 4; n++)
            gl_lds16(pa + k0 + (size_t)(n * 8) * lda, lA + n * 8 * 64);
#pragma unroll
        for (int n = 0; n < NB; n++)
            gl_lds16(pb + k0 + (size_t)(n * 8) * ldb, lB + n * 8 * 64);
        __syncthreads();
#pragma unroll
        for (int h = 0; h < 2; h++) {
            const int rb = h ? rblk1 : rblk0;
            bf16x8 af[TM], bfr[4];
#pragma unroll
            for (int i = 0; i < TM; i++)
                af[i] = *(const bf16x8*)&As[(wm + i * 16 + cl) * 64 + rb];
#pragma unroll
            for (int j = 0; j < 4; j++)
                bfr[j] = *(const bf16x8*)&Bs[(wn + j * 16 + cl) * 64 + rb];
#pragma unroll
            for (int i = 0; i < TM; i++)
#pragma unroll
                for (int j = 0; j < 4; j++)
                    acc[i][j] = __builtin_amdgcn_mfma_f32_16x16x32_bf16(af[i], bfr[j], acc[i][j], 0, 0, 0);
        }
        __syncthreads();
    }

    if constexpr (EPI == 4 || EPI == 5) {
        float inv[4], cs[4] = {0.f, 0.f, 0.f, 0.f};
        if constexpr (EPI == 5) {
#pragma unroll
            for (int j = 0; j < 4; j++)
                inv[j] = 1.0f / rowsum[(size_t)blockIdx.z * SS + n0 + wn + j * 16 + cl];
        }
#pragma unroll
        for (int i = 0; i < TM; i++)
#pragma unroll
            for (int j = 0; j < 4; j++) {
                int col = n0 + wn + j * 16 + cl;
                int row = m0 + wm + i * 16 + q * 4;
                bf16x4 o;
                if constexpr (EPI == 4) {
#pragma unroll
                    for (int r = 0; r < 4; r++) {
                        float e = __expf(acc[i][j][r] * scale);
                        cs[j] += e;
                        o[r] = (bf16)e;
                    }
                } else {
#pragma unroll
                    for (int r = 0; r < 4; r++) o[r] = (bf16)(acc[i][j][r] * inv[j]);
                }
                *(bf16x4*)&((bf16*)Cv)[(size_t)blockIdx.z * cb + (size_t)col * ldc + row] = o;
            }
        if constexpr (EPI == 4) {
#pragma unroll
            for (int j = 0; j < 4; j++) {
                cs[j] += __shfl_xor(cs[j], 16, 64);
                cs[j] += __shfl_xor(cs[j], 32, 64);
            }
            if (q == 0) {
#pragma unroll
                for (int j = 0; j < 4; j++)
                    atomicAdd(&rowsum[(size_t)blockIdx.z * SS + n0 + wn + j * 16 + cl], cs[j]);
            }
        }
        return;
    }
}

// distinct names so rocprof reports per-role counters
__global__ __launch_bounds__(512, 2) void k_qkv(const bf16* A, const bf16* Bm,
        const float* bias, bf16* vTp, void* Cv, int K, int lda, int ldb, int ldc,
        float scale) {
    gemm256_body<true, 3>(A, Bm, bias, nullptr, vTp, Cv, K, lda, ldb, ldc, 0, 0, 0, scale);
}
__global__ __launch_bounds__(512, 2) void k_score(const bf16* A, const bf16* Bm,
        float* rowsum, void* Cv, int K, int lda, int ldb, int ldc,
        long ab, long bb, long cb, float scale) {
    gemm256_body<true, 4>(A, Bm, nullptr, rowsum, nullptr, Cv, K, lda, ldb, ldc, ab, bb, cb, scale);
}
__global__ __launch_bounds__(256) void k_pv(const bf16* A, const bf16* Bm,
        float* rowsum, void* Cv, int K, int lda, int ldb, int ldc,
        long ab, long bb, long cb, float scale) {
    gemm_body<true, 64, 5>(A, Bm, nullptr, rowsum, nullptr, Cv, K, lda, ldb, ldc, ab, bb, cb, scale);
}
__global__ __launch_bounds__(512, 2) void k_out(const bf16* A, const bf16* Bm,
        const float* bias, void* Cv, int K, int lda, int ldb, int ldc,
        float scale) {
    gemm256_body<false, 0>(A, Bm, bias, nullptr, nullptr, Cv, K, lda, ldb, ldc, 0, 0, 0, scale);
}

// ---------------------------------------------------------------------------
extern "C" void kernel_launch(void* const* d_in, const int* in_sizes, int n_in,
                              void* d_out, int out_size, void* d_ws, size_t ws_size,
                              hipStream_t stream) {
    const float* x    = (const float*)d_in[0];  // (4,2048,2048)
    const float* Wqkv = (const float*)d_in[1];  // (1536,2048)
    const float* bqkv = (const float*)d_in[2];  // (1536,)
    const float* Wo   = (const float*)d_in[3];  // (2048,512)
    const float* bo   = (const float*)d_in[4];  // (2048,)
    float* out = (float*)d_out;                 // (4,2048,2048) fp32

    char* ws = (char*)d_ws;
    size_t off = 0;
    bf16* xb    = (bf16*)(ws + off); off += (size_t)MM * CC * 2;       // 32 MB
    bf16* wqkvb = (bf16*)(ws + off); off += (size_t)ND3 * CC * 2;      // 6 MB
    bf16* wob   = (bf16*)(ws + off); off += (size_t)CC * DD * 2;       // 2 MB
    bf16* qkvb  = (bf16*)(ws + off); off += (size_t)MM * ND3 * 2;      // 24 MB
    bf16* vT    = (bf16*)(ws + off); off += (size_t)BB * DD * SS * 2;  // 8 MB
    bf16* expS  = (bf16*)(ws + off); off += (size_t)BB * SS * SS * 2;  // 32 MB
    bf16* ctxb  = (bf16*)(ws + off); off += (size_t)MM * DD * 2;       // 8 MB
    float* rsum = (float*)(ws + off); off += (size_t)MM * 4;           // 32 KB

    // allow 128 KiB dynamic LDS on the ring-pipelined kernels
    static int lds_attr_set = 0;
    if (!lds_attr_set) {
        hipFuncSetAttribute((const void*)k_qkv,
                            hipFuncAttributeMaxDynamicSharedMemorySize, 131072);
        hipFuncSetAttribute((const void*)k_score,
                            hipFuncAttributeMaxDynamicSharedMemorySize, 131072);
        hipFuncSetAttribute((const void*)k_out,
                            hipFuncAttributeMaxDynamicSharedMemorySize, 131072);
        lds_attr_set = 1;
    }

    // 1. convert inputs to bf16 + zero rsum
    prep<<<2048, 256, 0, stream>>>(x, Wqkv, Wo, xb, wqkvb, wob, rsum);

    // 2. qkv = x Wqkv^T + bqkv; q,k -> qkvb rows, v -> vT transposed
    k_qkv<<<dim3(ND3 / 256, MM / 256, 1), 512, 131072, stream>>>(
        xb, wqkvb, bqkv, vT, qkvb, CC, CC, CC, ND3, 1.0f);

    // 3. expS[q][k] = exp(q k^T / sqrt(d)) via S^T = k q^T; col-sum atomics
    k_score<<<dim3(SS / 256, SS / 256, BB), 512, 131072, stream>>>(
        qkvb + 512 /*k*/, qkvb /*q*/, rsum, expS,
        DD, ND3, ND3, SS,
        (long)SS * ND3, (long)SS * ND3, (long)SS * SS,
        0.044194173824159216f /* 1/sqrt(512) */);

    // 4. ctx[q][d] via ctx^T = vT expS^T; /rowsum[col]; packed stores
    k_pv<<<dim3(SS / 64, DD / 128, BB), 256, 0, stream>>>(
        vT, expS, rsum, ctxb,
        SS, SS, SS, DD,
        (long)DD * SS, (long)SS * SS, (long)SS * DD, 1.0f);

    // 5. out = ctx Wo^T + bo  (M=8192, N=2048, K=512) -> fp32
    k_out<<<dim3(CC / 256, MM / 256, 1), 512, 131072, stream>>>(
        ctxb, wob, bo, out, DD, DD, DD, CC, 1.0f);

    (void)in_sizes; (void)n_in; (void)out_size; (void)ws_size;
}

// Round 3
// 269.670 us; speedup vs baseline: 1.0567x; 1.0567x over previous
//
#include <hip/hip_runtime.h>
#include <math.h>

// ---------------------------------------------------------------------------
// SingleHeadSelfAttention: B=4, S=2048, C=2048, d=512
// R9: - score/out revert to the R7 monophase ring schedule (R8's sub-phase
//       split regressed: +1 barrier/2 drains per chunk, no overlap unlocked).
//     - k_qkv: 256x192 tile -> grid 8x32 = 256 wgs (was 192 on 256 CUs: 25%
//       of the chip idle), NF=3 accs free 32 regs which fund a register
//       A-prefetch: chunk j issues FRAGS_A(j+1) into an alternate reg set
//       BEFORE MFMAing chunk j, hiding the 8-read A block under the MFMA
//       cluster by construction. Steady-state vmcnt(4) (per-wave loads are
//       non-uniform 4/3 due to the 1.5-instr B stage; proof below).
// ---------------------------------------------------------------------------

typedef __bf16 bf16;
typedef bf16 bf16x8 __attribute__((ext_vector_type(8)));
typedef bf16 bf16x4 __attribute__((ext_vector_type(4)));
typedef float f32x4 __attribute__((ext_vector_type(4)));

#define BB 4
#define SS 2048
#define CC 2048
#define DD 512
#define ND3 1536          // 3*DD
#define MM 8192           // BB*SS

typedef const __attribute__((address_space(1))) unsigned int g_u32;
typedef __attribute__((address_space(3))) unsigned int l_u32;

__device__ __forceinline__ void gl_lds16(const bf16* g, bf16* l) {
    __builtin_amdgcn_global_load_lds((g_u32*)g, (l_u32*)l, 16, 0, 0);
}

#define VMW(n) asm volatile("s_waitcnt vmcnt(" #n ")" ::: "memory")
#define LKW0   asm volatile("s_waitcnt lgkmcnt(0)" ::: "memory")
#define BAR    __builtin_amdgcn_s_barrier()

// ---------------- prep: fp32->bf16 for x/Wqkv/Wo + zero rsum ---------------
#define N4_X   (MM * CC / 4)          // 4194304
#define N4_WQ  (ND3 * CC / 4)         //  786432
#define N4_WO  (CC * DD / 4)          //  262144
#define N4_RS  (MM / 4)               //    2048
#define N4_TOT (N4_X + N4_WQ + N4_WO + N4_RS)

__global__ __launch_bounds__(256) void prep(const float* __restrict__ x,
                                            const float* __restrict__ Wqkv,
                                            const float* __restrict__ Wo,
                                            bf16* __restrict__ xb,
                                            bf16* __restrict__ wqkvb,
                                            bf16* __restrict__ wob,
                                            float* __restrict__ rsum) {
    int i = blockIdx.x * 256 + threadIdx.x;
    const int stride = gridDim.x * 256;
    for (; i < N4_TOT; i += stride) {
        if (i < N4_X + N4_WQ + N4_WO) {
            const float* src; bf16* dst; int j = i;
            if (j < N4_X)                { src = x;    dst = xb; }
            else if (j < N4_X + N4_WQ)   { src = Wqkv; dst = wqkvb; j -= N4_X; }
            else                         { src = Wo;   dst = wob;   j -= N4_X + N4_WQ; }
            float4 v = ((const float4*)src)[j];
            bf16x4 o;
            o[0] = (bf16)v.x; o[1] = (bf16)v.y; o[2] = (bf16)v.z; o[3] = (bf16)v.w;
            ((bf16x4*)dst)[j] = o;
        } else {
            int j = i - (N4_X + N4_WQ + N4_WO);
            ((float4*)rsum)[j] = float4{0.f, 0.f, 0.f, 0.f};
        }
    }
}

// ---------------------------------------------------------------------------
// k_qkv core: 256x192 tile, 8 waves (2Mx4N), per-wave 128x48 (acc[8][3]).
// K in 32-col chunks, 4-slot LDS ring: slot = A(256x32)@0 + B(192x32)@8192
// = 14336 el = 28 KiB; x4 slots = 112 KiB dynamic LDS.
// Chunk j body: FRAGS_B(j) (3 ds_read) | FRAGS_A(j+1)->alt regs (8 ds_read)
//   | STAGE(j+3) | 24 MFMA from current regs (A-reads of j+1 overlap these)
//   | vmcnt(4); lgkmcnt(0); barrier.
// vmcnt(4) proof (per-wave loads: w0-3: 4/chunk {A,A,B1,B2}, w4-7: 3/chunk
// {A,A,B1}): after staging c+3, newest-4 outstanding for w0-3 = all of c+3
// => c+2 fully landed; for w4-7 = c+3{A,A,B1} + c+2{B1} => c+2 A landed
// (needed for FRAGS_A(c+2) next chunk) and c+1 B landed (needed for
// FRAGS_B(c+1) next chunk). Slot overwrite: STAGE(c+3) hits slot (c-1)&3,
// whose reads were lgkm-drained by every wave before the previous barrier.
// Tail: vmcnt(4) at NC-4, vmcnt(0) at NC-3, none after.
// Swizzle: identical both-sides XOR involution as the 256 core.
// ---------------------------------------------------------------------------
#define SLOT3_E 14336

__global__ __launch_bounds__(512, 2) void k_qkv(const bf16* __restrict__ A,
        const bf16* __restrict__ Bm, const float* __restrict__ bias,
        bf16* __restrict__ vTp, bf16* __restrict__ Cv,
        int K, int lda, int ldb, int ldc) {
    extern __shared__ bf16 lds[];
    const int m0 = blockIdx.y * 256, n0 = blockIdx.x * 192;
    const int t = threadIdx.x, lane = t & 63, w = t >> 6;
    const int wm = (w >> 2) * 128, wn = (w & 3) * 48;
    const int cl = lane & 15, q = lane >> 4;
    const int swzr = (q ^ ((cl >> 1) & 3)) * 8;
    const int srow = t >> 2;
    const int swz  = (t & 3) ^ ((t >> 3) & 3);
    const bf16* pa = A  + (size_t)(m0 + srow) * lda + swz * 8;
    const bf16* pb = Bm + (size_t)(n0 + srow) * ldb + swz * 8;
    bf16* lw = lds + w * 512;

    f32x4 acc[8][3] = {};
    const int NC = K >> 5;                             // 64

    auto STAGE = [&](int j) {
        bf16* s = lw + (j & 3) * SLOT3_E;
        const bf16* ga = pa + j * 32;
        const bf16* gb = pb + j * 32;
        gl_lds16(ga,                     s);
        gl_lds16(ga + (size_t)128 * lda, s + 4096);
        gl_lds16(gb,                     s + 8192);
        if (w < 4) gl_lds16(gb + (size_t)128 * ldb, s + 8192 + 4096);
    };
    auto FRAGS_A = [&](int j, bf16x8 (&fa)[8]) {
        const bf16* sa = lds + (j & 3) * SLOT3_E + (wm + cl) * 32 + swzr;
#pragma unroll
        for (int i = 0; i < 8; i++) fa[i] = *(const bf16x8*)(sa + i * 512);
    };
    auto FRAGS_B = [&](int j, bf16x8 (&fb)[3]) {
        const bf16* sb = lds + (j & 3) * SLOT3_E + 8192 + (wn + cl) * 32 + swzr;
#pragma unroll
        for (int jj = 0; jj < 3; jj++) fb[jj] = *(const bf16x8*)(sb + jj * 512);
    };
    auto MFMAS3 = [&](bf16x8 (&fa)[8], bf16x8 (&fb)[3]) {
        __builtin_amdgcn_s_setprio(1);
#pragma unroll
        for (int i = 0; i < 8; i++)
#pragma unroll
            for (int jj = 0; jj < 3; jj++)
                acc[i][jj] = __builtin_amdgcn_mfma_f32_16x16x32_bf16(
                                 fa[i], fb[jj], acc[i][jj], 0, 0, 0);
        __builtin_amdgcn_s_setprio(0);
    };

#define QCHUNK(j, FCUR, FNXT, DO_NEXT, DO_STAGE)                              \
    {                                                                         \
        bf16x8 fb[3];                                                         \
        FRAGS_B((j), fb);                                                     \
        if (DO_NEXT) FRAGS_A((j) + 1, FNXT);                                  \
        if (DO_STAGE) STAGE((j) + 3);                                         \
        MFMAS3(FCUR, fb);                                                     \
    }

    STAGE(0); STAGE(1); STAGE(2);
    VMW(4); BAR;                      // chunk 0 full + chunk 1 A landed
    bf16x8 fa0[8], fa1[8];
    FRAGS_A(0, fa0);
    for (int j = 0; j < NC - 4; j += 2) {
        QCHUNK(j,     fa0, fa1, true, true);  VMW(4); LKW0; BAR;
        QCHUNK(j + 1, fa1, fa0, true, true);  VMW(4); LKW0; BAR;
    }
    QCHUNK(NC - 4, fa0, fa1, true, true);   VMW(4); LKW0; BAR;
    QCHUNK(NC - 3, fa1, fa0, true, false);  VMW(0); LKW0; BAR;
    QCHUNK(NC - 2, fa0, fa1, true, false);  LKW0; BAR;
    QCHUNK(NC - 1, fa1, fa0, false, false);
#undef QCHUNK

    // epilogue: col<1024 -> qkvb row-major; col>=1024 -> vT transposed.
    // 192-wide tiles straddle the 1024 boundary -> per-jj decision (16-col
    // groups never straddle: boundary and all group starts are x16).
#pragma unroll
    for (int i = 0; i < 8; i++) {
#pragma unroll
        for (int jj = 0; jj < 3; jj++) {
            int colg = n0 + wn + jj * 16;
            int col = colg + cl;
            float bvv = bias[col];
            if (colg >= 1024) {
                int row = m0 + wm + i * 16 + q * 4;
                int b = row >> 11, s = row & 2047;
                bf16x4 o;
#pragma unroll
                for (int r = 0; r < 4; r++) o[r] = (bf16)(acc[i][jj][r] + bvv);
                *(bf16x4*)&vTp[((size_t)b * DD + (col - 1024)) * SS + s] = o;
            } else {
#pragma unroll
                for (int r = 0; r < 4; r++) {
                    int row = m0 + wm + i * 16 + q * 4 + r;
                    Cv[(size_t)row * ldc + col] = (bf16)(acc[i][jj][r] + bvv);
                }
            }
        }
    }
}

// ---------------------------------------------------------------------------
// 256x256 monophase ring core (R7, verified best) for score/out.
// Chunk j: 12 ds_read | STAGE(j+3) (4 gl_lds) | 32 MFMA | vmcnt(8) | barrier.
// ---------------------------------------------------------------------------
#define SLOT_E 16384
#define CH_B   8192

template <bool OUT_BF16, int EPI>
__device__ __forceinline__ void gemm256_body(const bf16* __restrict__ A,
                                             const bf16* __restrict__ Bm,
                                             const float* __restrict__ bias,
                                             float* __restrict__ rowsum,
                                             void* __restrict__ Cv,
                                             int K, int lda, int ldb, int ldc,
                                             long ab, long bb, long cb,
                                             float scale) {
    extern __shared__ bf16 lds[];
    A  += (size_t)blockIdx.z * ab;
    Bm += (size_t)blockIdx.z * bb;
    const int m0 = blockIdx.y * 256, n0 = blockIdx.x * 256;
    const int t = threadIdx.x, lane = t & 63, w = t >> 6;
    const int wm = (w >> 2) * 128, wn = (w & 3) * 64;
    const int cl = lane & 15, q = lane >> 4;
    const int swzr = (q ^ ((cl >> 1) & 3)) * 8;
    const int srow = t >> 2;
    const int swz  = (t & 3) ^ ((t >> 3) & 3);
    const bf16* pa = A  + (size_t)(m0 + srow) * lda + swz * 8;
    const bf16* pb = Bm + (size_t)(n0 + srow) * ldb + swz * 8;
    bf16* lw = lds + w * 512;

    f32x4 acc[8][4] = {};
    const int NC = K >> 5;

    auto STAGE = [&](int j) {
        bf16* s = lw + (j & 3) * SLOT_E;
        const bf16* ga = pa + j * 32;
        const bf16* gb = pb + j * 32;
        gl_lds16(ga,                     s);
        gl_lds16(ga + (size_t)128 * lda, s + 4096);
        gl_lds16(gb,                     s + CH_B);
        gl_lds16(gb + (size_t)128 * ldb, s + CH_B + 4096);
    };
    auto FRAGS = [&](int j, bf16x8 (&af)[8], bf16x8 (&bfr)[4]) {
        const bf16* sa = lds + (j & 3) * SLOT_E + (wm + cl) * 32 + swzr;
        const bf16* sb = lds + (j & 3) * SLOT_E + CH_B + (wn + cl) * 32 + swzr;
#pragma unroll
        for (int i = 0; i < 8; i++)  af[i]  = *(const bf16x8*)(sa + i * 512);
#pragma unroll
        for (int jj = 0; jj < 4; jj++) bfr[jj] = *(const bf16x8*)(sb + jj * 512);
    };
    auto MFMAS = [&](bf16x8 (&af)[8], bf16x8 (&bfr)[4]) {
        __builtin_amdgcn_s_setprio(1);
#pragma unroll
        for (int i = 0; i < 8; i++)
#pragma unroll
            for (int jj = 0; jj < 4; jj++)
                acc[i][jj] = __builtin_amdgcn_mfma_f32_16x16x32_bf16(
                                 af[i], bfr[jj], acc[i][jj], 0, 0, 0);
        __builtin_amdgcn_s_setprio(0);
    };

    STAGE(0); STAGE(1); STAGE(2);
    VMW(8); BAR;

    for (int j = 0; j < NC - 3; ++j) {
        bf16x8 af[8], bfr[4];
        FRAGS(j, af, bfr);
        STAGE(j + 3);
        MFMAS(af, bfr);
        VMW(8); BAR;
    }
    {   bf16x8 af[8], bfr[4];
        FRAGS(NC - 3, af, bfr); MFMAS(af, bfr);
        VMW(4); BAR;
    }
    {   bf16x8 af[8], bfr[4];
        FRAGS(NC - 2, af, bfr); MFMAS(af, bfr);
        VMW(0); BAR;
    }
    {   bf16x8 af[8], bfr[4];
        FRAGS(NC - 1, af, bfr); MFMAS(af, bfr);
    }

    if constexpr (EPI == 4) {          // scoresT: exp, packed C^T, col-sums
        float cs[4] = {0.f, 0.f, 0.f, 0.f};
#pragma unroll
        for (int i = 0; i < 8; i++)
#pragma unroll
            for (int jj = 0; jj < 4; jj++) {
                int col = n0 + wn + jj * 16 + cl;
                int row = m0 + wm + i * 16 + q * 4;
                bf16x4 o;
#pragma unroll
                for (int r = 0; r < 4; r++) {
                    float e = __expf(acc[i][jj][r] * scale);
                    cs[jj] += e;
                    o[r] = (bf16)e;
                }
                *(bf16x4*)&((bf16*)Cv)[(size_t)blockIdx.z * cb + (size_t)col * ldc + row] = o;
            }
#pragma unroll
        for (int jj = 0; jj < 4; jj++) {
            cs[jj] += __shfl_xor(cs[jj], 16, 64);
            cs[jj] += __shfl_xor(cs[jj], 32, 64);
        }
        if (q == 0) {
#pragma unroll
            for (int jj = 0; jj < 4; jj++)
                atomicAdd(&rowsum[(size_t)blockIdx.z * SS + n0 + wn + jj * 16 + cl], cs[jj]);
        }
        return;
    }

#pragma unroll
    for (int i = 0; i < 8; i++) {
#pragma unroll
        for (int jj = 0; jj < 4; jj++) {
            int col = n0 + wn + jj * 16 + cl;
            float bvv = bias ? bias[col] : 0.0f;
#pragma unroll
            for (int r = 0; r < 4; r++) {
                int row = m0 + wm + i * 16 + q * 4 + r;
                float val = acc[i][jj][r] * scale + bvv;
                if (OUT_BF16)
                    ((bf16*)Cv)[(size_t)blockIdx.z * cb + (size_t)row * ldc + col] = (bf16)val;
                else
                    ((float*)Cv)[(size_t)blockIdx.z * cb + (size_t)row * ldc + col] = val;
            }
        }
    }
}

// ---------------------------------------------------------------------------
// OLD 128-tile core (verified) -- kept for k_pv only (BN=64, EPI=5).
// ---------------------------------------------------------------------------
template <int BN, int EPI>
__device__ __forceinline__ void gemm_body(const bf16* __restrict__ A,
                                          const bf16* __restrict__ Bm,
                                          float* __restrict__ rowsum,
                                          void* __restrict__ Cv,
                                          int K, int lda, int ldb, int ldc,
                                          long ab, long bb, long cb) {
    constexpr int TM = (BN == 128) ? 4 : 2;
    constexpr int NB = (BN == 128) ? 4 : 2;
    __shared__ bf16 As[128 * 64];
    __shared__ bf16 Bs[BN * 64];
    A += (size_t)blockIdx.z * ab;
    Bm += (size_t)blockIdx.z * bb;
    const int m0 = blockIdx.y * 128, n0 = blockIdx.x * BN;
    const int t = threadIdx.x, lane = t & 63, w = t >> 6;
    const int wm = (BN == 128) ? (w >> 1) * 64 : w * 32;
    const int wn = (BN == 128) ? (w & 1) * 64 : 0;
    const int q = lane >> 4, cl = lane & 15;
    const int srow = lane >> 3;
    const int sblk = (lane & 7) ^ srow;
    const int scol = sblk * 8;
    const bf16* pa = A + (size_t)(m0 + w * 32 + srow) * lda + scol;
    const int brow0 = (BN == 128) ? w * 32 : w * 16;
    const bf16* pb = Bm + (size_t)(n0 + brow0 + srow) * ldb + scol;
    bf16* lA = As + (w * 32) * 64;
    bf16* lB = Bs + brow0 * 64;
    const int rblk0 = (q ^ (cl & 7)) * 8;
    const int rblk1 = ((4 + q) ^ (cl & 7)) * 8;

    f32x4 acc[TM][4] = {};
    for (int k0 = 0; k0 < K; k0 += 64) {
#pragma unroll
        for (int n = 0; n < 4; n++)
            gl_lds16(pa + k0 + (size_t)(n * 8) * lda, lA + n * 8 * 64);
#pragma unroll
        for (int n = 0; n < NB; n++)
            gl_lds16(pb + k0 + (size_t)(n * 8) * ldb, lB + n * 8 * 64);
        __syncthreads();
#pragma unroll
        for (int h = 0; h < 2; h++) {
            const int rb = h ? rblk1 : rblk0;
            bf16x8 af[TM], bfr[4];
#pragma unroll
            for (int i = 0; i < TM; i++)
                af[i] = *(const bf16x8*)&As[(wm + i * 16 + cl) * 64 + rb];
#pragma unroll
            for (int j = 0; j < 4; j++)
                bfr[j] = *(const bf16x8*)&Bs[(wn + j * 16 + cl) * 64 + rb];
#pragma unroll
            for (int i = 0; i < TM; i++)
#pragma unroll
                for (int j = 0; j < 4; j++)
                    acc[i][j] = __builtin_amdgcn_mfma_f32_16x16x32_bf16(af[i], bfr[j], acc[i][j], 0, 0, 0);
        }
        __syncthreads();
    }

    float inv[4];
#pragma unroll
    for (int j = 0; j < 4; j++)
        inv[j] = 1.0f / rowsum[(size_t)blockIdx.z * SS + n0 + wn + j * 16 + cl];
#pragma unroll
    for (int i = 0; i < TM; i++)
#pragma unroll
        for (int j = 0; j < 4; j++) {
            int col = n0 + wn + j * 16 + cl;
            int row = m0 + wm + i * 16 + q * 4;
            bf16x4 o;
#pragma unroll
            for (int r = 0; r < 4; r++) o[r] = (bf16)(acc[i][j][r] * inv[j]);
            *(bf16x4*)&((bf16*)Cv)[(size_t)blockIdx.z * cb + (size_t)col * ldc + row] = o;
        }
}

// distinct names so rocprof reports per-role counters
__global__ __launch_bounds__(512, 2) void k_score(const bf16* A, const bf16* Bm,
        float* rowsum, void* Cv, int K, int lda, int ldb, int ldc,
        long ab, long bb, long cb, float scale) {
    gemm256_body<true, 4>(A, Bm, nullptr, rowsum, Cv, K, lda, ldb, ldc, ab, bb, cb, scale);
}
__global__ __launch_bounds__(256) void k_pv(const bf16* A, const bf16* Bm,
        float* rowsum, void* Cv, int K, int lda, int ldb, int ldc,
        long ab, long bb, long cb) {
    gemm_body<64, 5>(A, Bm, rowsum, Cv, K, lda, ldb, ldc, ab, bb, cb);
}
__global__ __launch_bounds__(512, 2) void k_out(const bf16* A, const bf16* Bm,
        const float* bias, void* Cv, int K, int lda, int ldb, int ldc,
        float scale) {
    gemm256_body<false, 0>(A, Bm, bias, nullptr, Cv, K, lda, ldb, ldc, 0, 0, 0, scale);
}

// ---------------------------------------------------------------------------
extern "C" void kernel_launch(void* const* d_in, const int* in_sizes, int n_in,
                              void* d_out, int out_size, void* d_ws, size_t ws_size,
                              hipStream_t stream) {
    const float* x    = (const float*)d_in[0];  // (4,2048,2048)
    const float* Wqkv = (const float*)d_in[1];  // (1536,2048)
    const float* bqkv = (const float*)d_in[2];  // (1536,)
    const float* Wo   = (const float*)d_in[3];  // (2048,512)
    const float* bo   = (const float*)d_in[4];  // (2048,)
    float* out = (float*)d_out;                 // (4,2048,2048) fp32

    char* ws = (char*)d_ws;
    size_t off = 0;
    bf16* xb    = (bf16*)(ws + off); off += (size_t)MM * CC * 2;       // 32 MB
    bf16* wqkvb = (bf16*)(ws + off); off += (size_t)ND3 * CC * 2;      // 6 MB
    bf16* wob   = (bf16*)(ws + off); off += (size_t)CC * DD * 2;       // 2 MB
    bf16* qkvb  = (bf16*)(ws + off); off += (size_t)MM * ND3 * 2;      // 24 MB
    bf16* vT    = (bf16*)(ws + off); off += (size_t)BB * DD * SS * 2;  // 8 MB
    bf16* expS  = (bf16*)(ws + off); off += (size_t)BB * SS * SS * 2;  // 32 MB
    bf16* ctxb  = (bf16*)(ws + off); off += (size_t)MM * DD * 2;       // 8 MB
    float* rsum = (float*)(ws + off); off += (size_t)MM * 4;           // 32 KB

    // allow 128 KiB dynamic LDS on the ring-pipelined kernels
    static int lds_attr_set = 0;
    if (!lds_attr_set) {
        hipFuncSetAttribute((const void*)k_qkv,
                            hipFuncAttributeMaxDynamicSharedMemorySize, 131072);
        hipFuncSetAttribute((const void*)k_score,
                            hipFuncAttributeMaxDynamicSharedMemorySize, 131072);
        hipFuncSetAttribute((const void*)k_out,
                            hipFuncAttributeMaxDynamicSharedMemorySize, 131072);
        lds_attr_set = 1;
    }

    // 1. convert inputs to bf16 + zero rsum
    prep<<<2048, 256, 0, stream>>>(x, Wqkv, Wo, xb, wqkvb, wob, rsum);

    // 2. qkv = x Wqkv^T + bqkv; q,k -> qkvb rows, v -> vT transposed
    //    256x192 tiles -> 8x32 = 256 wgs (exact CU coverage)
    k_qkv<<<dim3(ND3 / 192, MM / 256, 1), 512, 4 * SLOT3_E * 2, stream>>>(
        xb, wqkvb, bqkv, vT, qkvb, CC, CC, CC, ND3);

    // 3. expS[q][k] = exp(q k^T / sqrt(d)) via S^T = k q^T; col-sum atomics
    k_score<<<dim3(SS / 256, SS / 256, BB), 512, 131072, stream>>>(
        qkvb + 512 /*k*/, qkvb /*q*/, rsum, expS,
        DD, ND3, ND3, SS,
        (long)SS * ND3, (long)SS * ND3, (long)SS * SS,
        0.044194173824159216f /* 1/sqrt(512) */);

    // 4. ctx[q][d] via ctx^T = vT expS^T; /rowsum[col]; packed stores
    k_pv<<<dim3(SS / 64, DD / 128, BB), 256, 0, stream>>>(
        vT, expS, rsum, ctxb,
        SS, SS, SS, DD,
        (long)DD * SS, (long)SS * SS, (long)SS * DD);

    // 5. out = ctx Wo^T + bo  (M=8192, N=2048, K=512) -> fp32
    k_out<<<dim3(CC / 256, MM / 256, 1), 512, 131072, stream>>>(
        ctxb, wob, bo, out, DD, DD, DD, CC, 1.0f);

    (void)in_sizes; (void)n_in; (void)out_size; (void)ws_size;
}